// Round 10
// baseline (300.885 us; speedup 1.0000x reference)
//
#include <hip/hip_runtime.h>
#include <hip/hip_bf16.h>

typedef __attribute__((ext_vector_type(8))) short short8;
typedef __attribute__((ext_vector_type(4))) float floatx4;
typedef __attribute__((ext_vector_type(2))) float float2v;

__device__ __forceinline__ float leaky(float v){ return v > 0.f ? v : 0.1f*v; }
__device__ __forceinline__ void atomAdd(float* p, float v){ unsafeAtomicAdd(p, v); }
__device__ __forceinline__ short f2bf(float f){
  __hip_bfloat16 h = __float2bfloat16(f);
  return *reinterpret_cast<short*>(&h);
}

struct P {
  const float *x; const int *ei; const int *batch;
  const float *en1_w1,*en1_b1,*en1_w2,*en1_b2;
  const float *en2_w1,*en2_b1,*en2_w2,*en2_b2;
  const float *en3_w1,*en3_b1,*en3_w2,*en3_b2;
  const float *root1,*cb1,*root2,*cb2,*root3,*cb3;
  const float *fc1w,*fc1b,*fc2w,*fc2b,*fc3w,*fc3b;
  short *ef2b,*ef3b,*w2p2,*w2p3;
  float *a1,*a2,*a3,*g,*out;
  int N,E,Epad;
};

// Multi-role: blocks [0, Epad/4) do edge-features + conv1 (conv1 now parallel
// across all 256 threads via k-split + shuffle reduce);
// blocks [Epad/4, Epad/4+272) pack both w2 matrices into MFMA B-fragment order.
__global__ __launch_bounds__(256) void fused0(P p){
  int bid = blockIdx.x, tid = threadIdx.x;
  int nEf = p.Epad/4;
  if (bid < nEf){
    __shared__ float sm[4][64];
    int id = bid*256 + tid;
    int e = id >> 6, j = id & 63;
    float v1 = 0.f;
    if (e >= p.E){
      p.ef2b[id] = 0; p.ef3b[id] = 0;
    } else {
      int s = p.ei[e], d = p.ei[p.E+e];
      float4 xs = *reinterpret_cast<const float4*>(p.x + (size_t)s*4);
      float4 xd = *reinterpret_cast<const float4*>(p.x + (size_t)d*4);
      float d0 = xd.y - xs.y, d1 = xd.z - xs.z, d2 = xd.w - xs.w;
      v1 = leaky(d0*p.en1_w1[j] + d1*p.en1_w1[64+j] + d2*p.en1_w1[128+j] + p.en1_b1[j]);
      p.ef2b[id] = f2bf(leaky(d0*p.en2_w1[j] + d1*p.en2_w1[64+j] + d2*p.en2_w1[128+j] + p.en2_b1[j]));
      p.ef3b[id] = f2bf(leaky(d0*p.en3_w1[j] + d1*p.en3_w1[64+j] + d2*p.en3_w1[128+j] + p.en3_b1[j]));
    }
    sm[tid >> 6][j] = v1;
    __syncthreads();
    {
      int wv = tid >> 6;          // wave = local edge index
      int lane = tid & 63;
      int o = lane >> 3, kg = lane & 7;
      int ge = bid*4 + wv;
      float z0=0.f, z1=0.f, z2=0.f, z3=0.f;
      const float* smw = &sm[wv][kg*8];
      #pragma unroll
      for (int kk=0;kk<8;kk++){
        float a = smw[kk];
        const float* wp = p.en1_w2 + (kg*8+kk)*32 + o;
        z0 += a*wp[0]; z1 += a*wp[8]; z2 += a*wp[16]; z3 += a*wp[24];
      }
      #pragma unroll
      for (int d=1; d<8; d<<=1){
        z0 += __shfl_xor(z0, d);
        z1 += __shfl_xor(z1, d);
        z2 += __shfl_xor(z2, d);
        z3 += __shfl_xor(z3, d);
      }
      if (kg == 0 && ge < p.E){
        int s = p.ei[ge], dd = p.ei[p.E+ge];
        z0 += p.en1_b2[o]; z1 += p.en1_b2[8+o]; z2 += p.en1_b2[16+o]; z3 += p.en1_b2[24+o];
        float4 xv = *reinterpret_cast<const float4*>(p.x + (size_t)s*4);
        float msg = xv.x*leaky(z0) + xv.y*leaky(z1) + xv.z*leaky(z2) + xv.w*leaky(z3);
        atomAdd(&p.a1[(size_t)dd*8 + o], msg);
      }
    }
  } else {
    int pb = bid - nEf;                 // 0..271
    int lane = tid & 63;
    int c = pb*4 + (tid >> 6);          // 0..1087
    const float* w2; short* dst; int ICOC, OT, cc;
    if (c < 64){ w2 = p.en2_w2; dst = p.w2p2; ICOC = 512;  OT = 4; cc = c; }
    else       { w2 = p.en3_w2; dst = p.w2p3; ICOC = 8192; OT = 8; cc = c - 64; }
    int kh = cc & 1, rem = cc >> 1, otg = rem % OT, i = rem / OT;
    int n = lane & 15, q = lane >> 4;
    short o8[8];
    #pragma unroll
    for (int j=0;j<8;j++){
      int k = kh*32 + q*8 + j;
      o8[j] = f2bf(w2[(size_t)k*ICOC + i*(OT*16) + otg*16 + n]);
    }
    *reinterpret_cast<short8*>(dst + (size_t)cc*512 + lane*8) = *reinterpret_cast<short8*>(o8);
  }
}

// conv2 with node1 inlined into staging. 32 edges/block; MB=2, OT=4, WOT=1, ICB=8.
__global__ __launch_bounds__(256) void conv2k(P p){
  __shared__ float hsT[8][32];
  __shared__ int sdst[32];
  int tid = threadIdx.x;
  int eb = blockIdx.x*32;
  int E = p.E;
  {
    int e = tid & 31, i = tid >> 5;
    int ge = eb + e;
    bool valid = ge < E;
    int src = valid ? p.ei[ge] : 0;
    float hv = 0.f;
    if (valid){
      float4 xv = *reinterpret_cast<const float4*>(p.x + (size_t)src*4);
      float v = p.a1[(size_t)src*8 + i] + p.cb1[i]
              + xv.x*p.root1[i] + xv.y*p.root1[8+i] + xv.z*p.root1[16+i] + xv.w*p.root1[24+i];
      hv = leaky(v);
    }
    hsT[i][e] = hv;
    if (tid < 32) sdst[tid] = (eb + tid < E) ? p.ei[E + eb + tid] : -1;
  }
  __syncthreads();

  int lane = tid & 63, wv = tid >> 6;
  int n = lane & 15, quad = lane >> 4;
  int o0 = wv*16;
  short8 A[2][2];
  #pragma unroll
  for (int m=0;m<2;m++)
    #pragma unroll
    for (int kh=0;kh<2;kh++)
      A[m][kh] = *reinterpret_cast<const short8*>(p.ef2b + (size_t)(eb + m*16 + n)*64 + kh*32 + quad*8);

  float2v msg[2][2];
  msg[0][0]=(float2v){0.f,0.f}; msg[0][1]=(float2v){0.f,0.f};
  msg[1][0]=(float2v){0.f,0.f}; msg[1][1]=(float2v){0.f,0.f};

  auto loadB = [&](int ii, short8 (&Bt)[2], float &bz){
    int ig = (ii < 8) ? ii : 7;
    #pragma unroll
    for (int kh=0;kh<2;kh++)
      Bt[kh] = *reinterpret_cast<const short8*>(p.w2p2 + ((size_t)((ig*4 + wv)*2 + kh) << 9) + lane*8);
    bz = p.en2_b2[ig*64 + o0 + n];
  };
  auto compute = [&](int ii, short8 (&Bt)[2], float bz){
    #pragma unroll
    for (int m=0;m<2;m++){
      float4 hv = *reinterpret_cast<const float4*>(&hsT[ii][m*16 + quad*4]);
      float2v hvl = {hv.x, hv.y}, hvh = {hv.z, hv.w};
      floatx4 z = {bz, bz, bz, bz};
      z = __builtin_amdgcn_mfma_f32_16x16x32_bf16(A[m][0], Bt[0], z, 0, 0, 0);
      z = __builtin_amdgcn_mfma_f32_16x16x32_bf16(A[m][1], Bt[1], z, 0, 0, 0);
      float2v zl = {z[0], z[1]}, zh = {z[2], z[3]};
      float2v ll = __builtin_elementwise_max(zl, zl*0.1f);
      float2v lh = __builtin_elementwise_max(zh, zh*0.1f);
      msg[m][0] += hvl*ll;
      msg[m][1] += hvh*lh;
    }
  };

  short8 B0[2], B1[2]; float bz0, bz1;
  loadB(0, B0, bz0);
  #pragma unroll 2
  for (int i=0;i<8;i+=2){
    loadB(i+1, B1, bz1);
    compute(i, B0, bz0);
    loadB(i+2, B0, bz0);
    compute(i+1, B1, bz1);
  }

  #pragma unroll
  for (int m=0;m<2;m++)
    #pragma unroll
    for (int r=0;r<4;r++){
      int d = sdst[m*16 + quad*4 + r];
      if (d >= 0) atomAdd(&p.a2[(size_t)d*64 + o0 + n], msg[m][r>>1][r&1]);
    }
}

// conv3: 64 edges/block, 2-way ic-split (ICB=32). t0 = edge-tile offset so the
// kernel can be launched as two half dispatches (top-5 visibility + same work).
__global__ __launch_bounds__(256) void conv3k(P p, int t0){
  __shared__ float hsT[32][64];
  __shared__ int sdst[64];
  __shared__ float r2s[512];
  __shared__ float cb2s[64];
  int tid = threadIdx.x;
  int bi = blockIdx.x;
  int eb = ((bi >> 1) + t0)*64;
  int i0 = (bi & 1)*32;
  int E = p.E;

  r2s[tid]     = p.root2[tid];
  r2s[256+tid] = p.root2[256+tid];
  if (tid < 64) cb2s[tid] = p.cb2[tid];
  if (tid < 64) sdst[tid] = (eb + tid < E) ? p.ei[E + eb + tid] : -1;

  int e = tid & 63, c = tid >> 6;       // c in [0,4): 8 channels each
  int ge = eb + e;
  bool valid = ge < E;
  int src = valid ? p.ei[ge] : 0;
  float h1[8];
  {
    float4 xv  = *reinterpret_cast<const float4*>(p.x  + (size_t)src*4);
    float4 a1l = *reinterpret_cast<const float4*>(p.a1 + (size_t)src*8);
    float4 a1h = *reinterpret_cast<const float4*>(p.a1 + (size_t)src*8 + 4);
    float a1v[8] = {a1l.x,a1l.y,a1l.z,a1l.w,a1h.x,a1h.y,a1h.z,a1h.w};
    #pragma unroll
    for (int k=0;k<8;k++){
      float v = a1v[k] + p.cb1[k] + xv.x*p.root1[k] + xv.y*p.root1[8+k]
              + xv.z*p.root1[16+k] + xv.w*p.root1[24+k];
      h1[k] = leaky(v);
    }
  }
  __syncthreads();   // r2s/cb2s ready
  {
    int ib = i0 + c*8;
    float4 acc0 = *reinterpret_cast<const float4*>(p.a2 + (size_t)src*64 + ib);
    float4 acc1 = *reinterpret_cast<const float4*>(p.a2 + (size_t)src*64 + ib + 4);
    float4 cb0 = *reinterpret_cast<const float4*>(&cb2s[ib]);
    float4 cb1v = *reinterpret_cast<const float4*>(&cb2s[ib+4]);
    acc0.x+=cb0.x; acc0.y+=cb0.y; acc0.z+=cb0.z; acc0.w+=cb0.w;
    acc1.x+=cb1v.x; acc1.y+=cb1v.y; acc1.z+=cb1v.z; acc1.w+=cb1v.w;
    #pragma unroll
    for (int k=0;k<8;k++){
      float hk = h1[k];
      float4 r0 = *reinterpret_cast<const float4*>(&r2s[k*64+ib]);
      float4 r1 = *reinterpret_cast<const float4*>(&r2s[k*64+ib+4]);
      acc0.x += hk*r0.x; acc0.y += hk*r0.y; acc0.z += hk*r0.z; acc0.w += hk*r0.w;
      acc1.x += hk*r1.x; acc1.y += hk*r1.y; acc1.z += hk*r1.z; acc1.w += hk*r1.w;
    }
    hsT[c*8+0][e] = valid ? leaky(acc0.x) : 0.f;
    hsT[c*8+1][e] = valid ? leaky(acc0.y) : 0.f;
    hsT[c*8+2][e] = valid ? leaky(acc0.z) : 0.f;
    hsT[c*8+3][e] = valid ? leaky(acc0.w) : 0.f;
    hsT[c*8+4][e] = valid ? leaky(acc1.x) : 0.f;
    hsT[c*8+5][e] = valid ? leaky(acc1.y) : 0.f;
    hsT[c*8+6][e] = valid ? leaky(acc1.z) : 0.f;
    hsT[c*8+7][e] = valid ? leaky(acc1.w) : 0.f;
  }
  __syncthreads();

  int lane = tid & 63, wv = tid >> 6;
  int n = lane & 15, quad = lane >> 4;
  int o0 = wv*32;
  short8 A[4][2];
  #pragma unroll
  for (int m=0;m<4;m++)
    #pragma unroll
    for (int kh=0;kh<2;kh++)
      A[m][kh] = *reinterpret_cast<const short8*>(p.ef3b + (size_t)(eb + m*16 + n)*64 + kh*32 + quad*8);

  float2v msg[4][2][2];
  #pragma unroll
  for (int m=0;m<4;m++)
    #pragma unroll
    for (int t=0;t<2;t++){
      msg[m][t][0]=(float2v){0.f,0.f}; msg[m][t][1]=(float2v){0.f,0.f};
    }

  auto loadB = [&](int ii, short8 (&Bt)[2][2], float (&bzt)[2]){
    int il = (ii < 32) ? ii : 31;
    int ig = i0 + il;
    #pragma unroll
    for (int t=0;t<2;t++){
      int otg = wv*2 + t;
      #pragma unroll
      for (int kh=0;kh<2;kh++)
        Bt[t][kh] = *reinterpret_cast<const short8*>(p.w2p3 + ((size_t)((ig*8 + otg)*2 + kh) << 9) + lane*8);
      bzt[t] = p.en3_b2[ig*128 + o0 + t*16 + n];
    }
  };
  auto compute = [&](int ii, short8 (&Bt)[2][2], float (&bzt)[2]){
    #pragma unroll
    for (int m=0;m<4;m++){
      float4 hv = *reinterpret_cast<const float4*>(&hsT[ii][m*16 + quad*4]);
      float2v hvl = {hv.x, hv.y}, hvh = {hv.z, hv.w};
      #pragma unroll
      for (int t=0;t<2;t++){
        floatx4 z = {bzt[t], bzt[t], bzt[t], bzt[t]};
        z = __builtin_amdgcn_mfma_f32_16x16x32_bf16(A[m][0], Bt[t][0], z, 0, 0, 0);
        z = __builtin_amdgcn_mfma_f32_16x16x32_bf16(A[m][1], Bt[t][1], z, 0, 0, 0);
        float2v zl = {z[0], z[1]}, zh = {z[2], z[3]};
        float2v ll = __builtin_elementwise_max(zl, zl*0.1f);
        float2v lh = __builtin_elementwise_max(zh, zh*0.1f);
        msg[m][t][0] += hvl*ll;
        msg[m][t][1] += hvh*lh;
      }
    }
  };

  short8 B0[2][2], B1[2][2];
  float bz0[2], bz1[2];
  loadB(0, B0, bz0);
  #pragma unroll 2
  for (int i=0;i<32;i+=2){
    loadB(i+1, B1, bz1);
    compute(i, B0, bz0);
    loadB(i+2, B0, bz0);
    compute(i+1, B1, bz1);
  }

  #pragma unroll
  for (int m=0;m<4;m++)
    #pragma unroll
    for (int r=0;r<4;r++){
      int d = sdst[m*16 + quad*4 + r];
      if (d >= 0){
        #pragma unroll
        for (int t=0;t<2;t++)
          atomAdd(&p.a3[(size_t)d*128 + o0 + t*16 + n], msg[m][t][r>>1][r&1]);
      }
    }
}

// node3 + pool with h2 recomputed per node; 8 nodes/block (1000 blocks).
__global__ __launch_bounds__(256) void npk(P p){
  __shared__ float r3s[8192];
  __shared__ float r2s[512];
  __shared__ float cb2s[64];
  __shared__ float hrow[8][64];
  int tid = threadIdx.x;
  int N = p.N;
  for (int r=tid; r<2048; r+=256)
    reinterpret_cast<float4*>(r3s)[r] = reinterpret_cast<const float4*>(p.root3)[r];
  r2s[tid]     = p.root2[tid];
  r2s[256+tid] = p.root2[256+tid];
  if (tid < 64) cb2s[tid] = p.cb2[tid];
  __syncthreads();

  int n0 = blockIdx.x*8;
  {
    int nl = tid >> 5, c0 = (tid & 31)*2;   // 8 nodes x 32 threads, 2 ch each
    int n = n0 + nl;
    int nn = (n < N) ? n : 0;
    float4 xv  = *reinterpret_cast<const float4*>(p.x  + (size_t)nn*4);
    float4 a1l = *reinterpret_cast<const float4*>(p.a1 + (size_t)nn*8);
    float4 a1h = *reinterpret_cast<const float4*>(p.a1 + (size_t)nn*8 + 4);
    float a1v[8] = {a1l.x,a1l.y,a1l.z,a1l.w,a1h.x,a1h.y,a1h.z,a1h.w};
    float h1[8];
    #pragma unroll
    for (int k=0;k<8;k++){
      float v = a1v[k] + p.cb1[k] + xv.x*p.root1[k] + xv.y*p.root1[8+k]
              + xv.z*p.root1[16+k] + xv.w*p.root1[24+k];
      h1[k] = leaky(v);
    }
    float2 acc = *reinterpret_cast<const float2*>(p.a2 + (size_t)nn*64 + c0);
    acc.x += cb2s[c0]; acc.y += cb2s[c0+1];
    #pragma unroll
    for (int k=0;k<8;k++){
      float hk = h1[k];
      acc.x += hk*r2s[k*64+c0];
      acc.y += hk*r2s[k*64+c0+1];
    }
    hrow[nl][c0+0] = leaky(acc.x);
    hrow[nl][c0+1] = leaky(acc.y);
  }
  __syncthreads();

  int o = tid & 127, np_ = tid >> 7;
  float acc = 0.f; int cur = -1;
  for (int rep=0; rep<4; rep++){
    int nl = rep*2 + np_; int n = n0 + nl;
    if (n >= N) break;
    int b = p.batch[n];
    if (b != cur){ if (cur >= 0) atomAdd(&p.g[cur*128+o], acc); acc = 0.f; cur = b; }
    float v = p.a3[(size_t)n*128 + o] + p.cb3[o];
    #pragma unroll 16
    for (int i=0;i<64;i++) v += hrow[nl][i]*r3s[i*128+o];
    acc += leaky(v);
  }
  if (cur >= 0) atomAdd(&p.g[cur*128+o], acc);
}

// readout MLP: one block per graph
__global__ void head_kernel(P p){
  __shared__ float s1[128], s2[128];
  int gi = blockIdx.x, t = threadIdx.x;
  s1[t] = p.g[gi*128+t];
  __syncthreads();
  float v = p.fc1b[t];
  for (int i=0;i<128;i++) v += s1[i]*p.fc1w[i*128+t];
  s2[t] = leaky(v);
  __syncthreads();
  if (t < 64){
    float v2 = p.fc2b[t];
    for (int i=0;i<128;i++) v2 += s2[i]*p.fc2w[i*64+t];
    s1[t] = leaky(v2);
  }
  __syncthreads();
  if (t == 0){
    float v3 = p.fc3b[0];
    for (int i=0;i<64;i++) v3 += s1[i]*p.fc3w[i];
    p.out[gi] = v3;
  }
}

extern "C" void kernel_launch(void* const* d_in, const int* in_sizes, int n_in,
                              void* d_out, int out_size, void* d_ws, size_t ws_size,
                              hipStream_t stream) {
  P p;
  p.x      = (const float*)d_in[0];
  p.ei     = (const int*)  d_in[1];
  p.batch  = (const int*)  d_in[2];
  p.en1_w1 = (const float*)d_in[3];  p.en1_b1 = (const float*)d_in[4];
  p.en1_w2 = (const float*)d_in[5];  p.en1_b2 = (const float*)d_in[6];
  p.en2_w1 = (const float*)d_in[7];  p.en2_b1 = (const float*)d_in[8];
  p.en2_w2 = (const float*)d_in[9];  p.en2_b2 = (const float*)d_in[10];
  p.en3_w1 = (const float*)d_in[11]; p.en3_b1 = (const float*)d_in[12];
  p.en3_w2 = (const float*)d_in[13]; p.en3_b2 = (const float*)d_in[14];
  p.root1  = (const float*)d_in[15]; p.cb1    = (const float*)d_in[16];
  p.root2  = (const float*)d_in[17]; p.cb2    = (const float*)d_in[18];
  p.root3  = (const float*)d_in[19]; p.cb3    = (const float*)d_in[20];
  p.fc1w   = (const float*)d_in[21]; p.fc1b   = (const float*)d_in[22];
  p.fc2w   = (const float*)d_in[23]; p.fc2b   = (const float*)d_in[24];
  p.fc3w   = (const float*)d_in[25]; p.fc3b   = (const float*)d_in[26];
  p.out = (float*)d_out;

  p.N = in_sizes[0] / 4;
  p.E = in_sizes[1] / 2;
  p.Epad = (p.E + 63) & ~63;

  p.ef2b = (short*)d_ws;
  p.ef3b = p.ef2b + (size_t)p.Epad*64;
  p.w2p2 = p.ef3b + (size_t)p.Epad*64;
  p.w2p3 = p.w2p2 + 8*4*2*512;
  p.a1   = (float*)(p.w2p3 + 64*8*2*512);
  p.a2   = p.a1 + (size_t)p.N*8;
  p.a3   = p.a2 + (size_t)p.N*64;
  p.g    = p.a3 + (size_t)p.N*128;

  size_t zero_bytes = ((size_t)p.N*(8+64+128) + (size_t)32*128) * sizeof(float);
  hipMemsetAsync(p.a1, 0, zero_bytes, stream);

  fused0<<<p.Epad/4 + 272, 256, 0, stream>>>(p);
  conv2k<<<p.Epad/32, 256, 0, stream>>>(p);

  int tiles = p.Epad/64;                 // 500
  int half = (tiles + 1)/2;              // 250
  conv3k<<<half*2, 256, 0, stream>>>(p, 0);
  conv3k<<<(tiles - half)*2, 256, 0, stream>>>(p, half);

  npk<<<(p.N + 7)/8, 256, 0, stream>>>(p);
  head_kernel<<<32, 128, 0, stream>>>(p);
}

// Round 11
// 248.091 us; speedup vs baseline: 1.2128x; 1.2128x over previous
//
#include <hip/hip_runtime.h>
#include <hip/hip_bf16.h>

typedef __attribute__((ext_vector_type(8))) short short8;
typedef __attribute__((ext_vector_type(4))) float floatx4;
typedef __attribute__((ext_vector_type(2))) float float2v;

__device__ __forceinline__ float leaky(float v){ return v > 0.f ? v : 0.1f*v; }
__device__ __forceinline__ void atomAdd(float* p, float v){ unsafeAtomicAdd(p, v); }
__device__ __forceinline__ short f2bf(float f){
  __hip_bfloat16 h = __float2bfloat16(f);
  return *reinterpret_cast<short*>(&h);
}

struct P {
  const float *x; const int *ei; const int *batch;
  const float *en1_w1,*en1_b1,*en1_w2,*en1_b2;
  const float *en2_w1,*en2_b1,*en2_w2,*en2_b2;
  const float *en3_w1,*en3_b1,*en3_w2,*en3_b2;
  const float *root1,*cb1,*root2,*cb2,*root3,*cb3;
  const float *fc1w,*fc1b,*fc2w,*fc2b,*fc3w,*fc3b;
  short *ef2b,*ef3b,*w2p2,*w2p3;
  float *a1,*a2,*a3,*g,*out;
  int N,E,Epad;
};

// Multi-role. Blocks [0, Epad/64): edge-features + conv1 for 64 edges each,
// with ALL layer-1 weights staged in LDS once per block (kills the per-wave
// global gather storm that made the old version latency-bound).
// Blocks [Epad/64, +272): pack w2 matrices into MFMA B-fragment order.
__global__ __launch_bounds__(256) void fused0(P p){
  int bid = blockIdx.x, tid = threadIdx.x;
  int nEf = p.Epad/64;
  if (bid < nEf){
    __shared__ float w1s[3][192];
    __shared__ float b1s[3][64];
    __shared__ float w2s[2048];     // en1_w2 [64][32]
    __shared__ float b2s[32];
    __shared__ float sm[4][64];
    for (int idx = tid; idx < 576; idx += 256){
      int net = idx/192, r = idx%192;
      w1s[net][r] = (net==0 ? p.en1_w1 : net==1 ? p.en2_w1 : p.en3_w1)[r];
    }
    if (tid < 192){
      int net = tid >> 6, j = tid & 63;
      b1s[net][j] = (net==0 ? p.en1_b1 : net==1 ? p.en2_b1 : p.en3_b1)[j];
    }
    for (int idx = tid; idx < 2048; idx += 256) w2s[idx] = p.en1_w2[idx];
    if (tid < 32) b2s[tid] = p.en1_b2[tid];
    __syncthreads();

    int wv = tid >> 6, j = tid & 63;
    int o = j & 31, h = j >> 5;
    int e0 = bid*64;
    for (int it = 0; it < 16; it++){
      int e = e0 + it*4 + wv;
      bool valid = e < p.E;
      int s = valid ? p.ei[e] : 0;
      int d = valid ? p.ei[p.E+e] : 0;
      float4 xs = *reinterpret_cast<const float4*>(p.x + (size_t)s*4);
      float4 xd = *reinterpret_cast<const float4*>(p.x + (size_t)d*4);
      float d0 = xd.y - xs.y, d1 = xd.z - xs.z, d2 = xd.w - xs.w;
      float v1 = 0.f;
      if (valid){
        v1 = leaky(d0*w1s[0][j] + d1*w1s[0][64+j] + d2*w1s[0][128+j] + b1s[0][j]);
        p.ef2b[(size_t)e*64+j] = f2bf(leaky(d0*w1s[1][j] + d1*w1s[1][64+j] + d2*w1s[1][128+j] + b1s[1][j]));
        p.ef3b[(size_t)e*64+j] = f2bf(leaky(d0*w1s[2][j] + d1*w1s[2][64+j] + d2*w1s[2][128+j] + b1s[2][j]));
      } else {
        p.ef2b[(size_t)e*64+j] = 0;
        p.ef3b[(size_t)e*64+j] = 0;
      }
      sm[wv][j] = v1;   // wave-private row: no block barrier needed

      // conv1: z[o] = sum_k sm[k]*w2s[k][o]; k split across lane-halves.
      float za0=0.f, za1=0.f, za2=0.f, za3=0.f;
      const float* smw = &sm[wv][h*32];
      const float* wb = &w2s[(size_t)h*32*32 + o];
      #pragma unroll
      for (int k=0;k<32;k+=4){
        za0 += smw[k+0]*wb[(k+0)*32];
        za1 += smw[k+1]*wb[(k+1)*32];
        za2 += smw[k+2]*wb[(k+2)*32];
        za3 += smw[k+3]*wb[(k+3)*32];
      }
      float z = (za0+za1)+(za2+za3);
      z += __shfl_xor(z, 32);
      z = leaky(z + b2s[o]);
      float xi = (o<16) ? ((o<8)? xs.x : xs.y) : ((o<24)? xs.z : xs.w);
      float t = xi * z;
      t += __shfl_xor(t, 8);
      t += __shfl_xor(t, 16);
      if (h == 0 && o < 8 && valid)
        atomAdd(&p.a1[(size_t)d*8 + o], t);
    }
  } else {
    int pb = bid - nEf;                 // 0..271
    int lane = tid & 63;
    int c = pb*4 + (tid >> 6);          // 0..1087
    const float* w2; short* dst; int ICOC, OT, cc;
    if (c < 64){ w2 = p.en2_w2; dst = p.w2p2; ICOC = 512;  OT = 4; cc = c; }
    else       { w2 = p.en3_w2; dst = p.w2p3; ICOC = 8192; OT = 8; cc = c - 64; }
    int kh = cc & 1, rem = cc >> 1, otg = rem % OT, i = rem / OT;
    int n = lane & 15, q = lane >> 4;
    short o8[8];
    #pragma unroll
    for (int jj=0;jj<8;jj++){
      int k = kh*32 + q*8 + jj;
      o8[jj] = f2bf(w2[(size_t)k*ICOC + i*(OT*16) + otg*16 + n]);
    }
    *reinterpret_cast<short8*>(dst + (size_t)cc*512 + lane*8) = *reinterpret_cast<short8*>(o8);
  }
}

// conv2 with node1 inlined into staging. 32 edges/block; MB=2, OT=4, WOT=1, ICB=8.
__global__ __launch_bounds__(256) void conv2k(P p){
  __shared__ float hsT[8][32];
  __shared__ int sdst[32];
  int tid = threadIdx.x;
  int eb = blockIdx.x*32;
  int E = p.E;
  {
    int e = tid & 31, i = tid >> 5;
    int ge = eb + e;
    bool valid = ge < E;
    int src = valid ? p.ei[ge] : 0;
    float hv = 0.f;
    if (valid){
      float4 xv = *reinterpret_cast<const float4*>(p.x + (size_t)src*4);
      float v = p.a1[(size_t)src*8 + i] + p.cb1[i]
              + xv.x*p.root1[i] + xv.y*p.root1[8+i] + xv.z*p.root1[16+i] + xv.w*p.root1[24+i];
      hv = leaky(v);
    }
    hsT[i][e] = hv;
    if (tid < 32) sdst[tid] = (eb + tid < E) ? p.ei[E + eb + tid] : -1;
  }
  __syncthreads();

  int lane = tid & 63, wv = tid >> 6;
  int n = lane & 15, quad = lane >> 4;
  int o0 = wv*16;
  short8 A[2][2];
  #pragma unroll
  for (int m=0;m<2;m++)
    #pragma unroll
    for (int kh=0;kh<2;kh++)
      A[m][kh] = *reinterpret_cast<const short8*>(p.ef2b + (size_t)(eb + m*16 + n)*64 + kh*32 + quad*8);

  float2v msg[2][2];
  msg[0][0]=(float2v){0.f,0.f}; msg[0][1]=(float2v){0.f,0.f};
  msg[1][0]=(float2v){0.f,0.f}; msg[1][1]=(float2v){0.f,0.f};

  auto loadB = [&](int ii, short8 (&Bt)[2], float &bz){
    int ig = (ii < 8) ? ii : 7;
    #pragma unroll
    for (int kh=0;kh<2;kh++)
      Bt[kh] = *reinterpret_cast<const short8*>(p.w2p2 + ((size_t)((ig*4 + wv)*2 + kh) << 9) + lane*8);
    bz = p.en2_b2[ig*64 + o0 + n];
  };
  auto compute = [&](int ii, short8 (&Bt)[2], float bz){
    #pragma unroll
    for (int m=0;m<2;m++){
      float4 hv = *reinterpret_cast<const float4*>(&hsT[ii][m*16 + quad*4]);
      float2v hvl = {hv.x, hv.y}, hvh = {hv.z, hv.w};
      floatx4 z = {bz, bz, bz, bz};
      z = __builtin_amdgcn_mfma_f32_16x16x32_bf16(A[m][0], Bt[0], z, 0, 0, 0);
      z = __builtin_amdgcn_mfma_f32_16x16x32_bf16(A[m][1], Bt[1], z, 0, 0, 0);
      float2v zl = {z[0], z[1]}, zh = {z[2], z[3]};
      float2v ll = __builtin_elementwise_max(zl, zl*0.1f);
      float2v lh = __builtin_elementwise_max(zh, zh*0.1f);
      msg[m][0] += hvl*ll;
      msg[m][1] += hvh*lh;
    }
  };

  short8 B0[2], B1[2]; float bz0, bz1;
  loadB(0, B0, bz0);
  #pragma unroll 2
  for (int i=0;i<8;i+=2){
    loadB(i+1, B1, bz1);
    compute(i, B0, bz0);
    loadB(i+2, B0, bz0);
    compute(i+1, B1, bz1);
  }

  #pragma unroll
  for (int m=0;m<2;m++)
    #pragma unroll
    for (int r=0;r<4;r++){
      int d = sdst[m*16 + quad*4 + r];
      if (d >= 0) atomAdd(&p.a2[(size_t)d*64 + o0 + n], msg[m][r>>1][r&1]);
    }
}

// conv3: 64 edges/block, 2-way ic-split (ICB=32); node1+node2 recomputed in staging.
__global__ __launch_bounds__(256) void conv3k(P p){
  __shared__ float hsT[32][64];
  __shared__ int sdst[64];
  __shared__ float r2s[512];
  __shared__ float cb2s[64];
  int tid = threadIdx.x;
  int bi = blockIdx.x;
  int eb = (bi >> 1)*64;
  int i0 = (bi & 1)*32;
  int E = p.E;

  r2s[tid]     = p.root2[tid];
  r2s[256+tid] = p.root2[256+tid];
  if (tid < 64) cb2s[tid] = p.cb2[tid];
  if (tid < 64) sdst[tid] = (eb + tid < E) ? p.ei[E + eb + tid] : -1;

  int e = tid & 63, c = tid >> 6;       // c in [0,4): 8 channels each
  int ge = eb + e;
  bool valid = ge < E;
  int src = valid ? p.ei[ge] : 0;
  float h1[8];
  {
    float4 xv  = *reinterpret_cast<const float4*>(p.x  + (size_t)src*4);
    float4 a1l = *reinterpret_cast<const float4*>(p.a1 + (size_t)src*8);
    float4 a1h = *reinterpret_cast<const float4*>(p.a1 + (size_t)src*8 + 4);
    float a1v[8] = {a1l.x,a1l.y,a1l.z,a1l.w,a1h.x,a1h.y,a1h.z,a1h.w};
    #pragma unroll
    for (int k=0;k<8;k++){
      float v = a1v[k] + p.cb1[k] + xv.x*p.root1[k] + xv.y*p.root1[8+k]
              + xv.z*p.root1[16+k] + xv.w*p.root1[24+k];
      h1[k] = leaky(v);
    }
  }
  __syncthreads();   // r2s/cb2s ready
  {
    int ib = i0 + c*8;
    float4 acc0 = *reinterpret_cast<const float4*>(p.a2 + (size_t)src*64 + ib);
    float4 acc1 = *reinterpret_cast<const float4*>(p.a2 + (size_t)src*64 + ib + 4);
    float4 cb0 = *reinterpret_cast<const float4*>(&cb2s[ib]);
    float4 cb1v = *reinterpret_cast<const float4*>(&cb2s[ib+4]);
    acc0.x+=cb0.x; acc0.y+=cb0.y; acc0.z+=cb0.z; acc0.w+=cb0.w;
    acc1.x+=cb1v.x; acc1.y+=cb1v.y; acc1.z+=cb1v.z; acc1.w+=cb1v.w;
    #pragma unroll
    for (int k=0;k<8;k++){
      float hk = h1[k];
      float4 r0 = *reinterpret_cast<const float4*>(&r2s[k*64+ib]);
      float4 r1 = *reinterpret_cast<const float4*>(&r2s[k*64+ib+4]);
      acc0.x += hk*r0.x; acc0.y += hk*r0.y; acc0.z += hk*r0.z; acc0.w += hk*r0.w;
      acc1.x += hk*r1.x; acc1.y += hk*r1.y; acc1.z += hk*r1.z; acc1.w += hk*r1.w;
    }
    hsT[c*8+0][e] = valid ? leaky(acc0.x) : 0.f;
    hsT[c*8+1][e] = valid ? leaky(acc0.y) : 0.f;
    hsT[c*8+2][e] = valid ? leaky(acc0.z) : 0.f;
    hsT[c*8+3][e] = valid ? leaky(acc0.w) : 0.f;
    hsT[c*8+4][e] = valid ? leaky(acc1.x) : 0.f;
    hsT[c*8+5][e] = valid ? leaky(acc1.y) : 0.f;
    hsT[c*8+6][e] = valid ? leaky(acc1.z) : 0.f;
    hsT[c*8+7][e] = valid ? leaky(acc1.w) : 0.f;
  }
  __syncthreads();

  int lane = tid & 63, wv = tid >> 6;
  int n = lane & 15, quad = lane >> 4;
  int o0 = wv*32;
  short8 A[4][2];
  #pragma unroll
  for (int m=0;m<4;m++)
    #pragma unroll
    for (int kh=0;kh<2;kh++)
      A[m][kh] = *reinterpret_cast<const short8*>(p.ef3b + (size_t)(eb + m*16 + n)*64 + kh*32 + quad*8);

  float2v msg[4][2][2];
  #pragma unroll
  for (int m=0;m<4;m++)
    #pragma unroll
    for (int t=0;t<2;t++){
      msg[m][t][0]=(float2v){0.f,0.f}; msg[m][t][1]=(float2v){0.f,0.f};
    }

  auto loadB = [&](int ii, short8 (&Bt)[2][2], float (&bzt)[2]){
    int il = (ii < 32) ? ii : 31;
    int ig = i0 + il;
    #pragma unroll
    for (int t=0;t<2;t++){
      int otg = wv*2 + t;
      #pragma unroll
      for (int kh=0;kh<2;kh++)
        Bt[t][kh] = *reinterpret_cast<const short8*>(p.w2p3 + ((size_t)((ig*8 + otg)*2 + kh) << 9) + lane*8);
      bzt[t] = p.en3_b2[ig*128 + o0 + t*16 + n];
    }
  };
  auto compute = [&](int ii, short8 (&Bt)[2][2], float (&bzt)[2]){
    #pragma unroll
    for (int m=0;m<4;m++){
      float4 hv = *reinterpret_cast<const float4*>(&hsT[ii][m*16 + quad*4]);
      float2v hvl = {hv.x, hv.y}, hvh = {hv.z, hv.w};
      #pragma unroll
      for (int t=0;t<2;t++){
        floatx4 z = {bzt[t], bzt[t], bzt[t], bzt[t]};
        z = __builtin_amdgcn_mfma_f32_16x16x32_bf16(A[m][0], Bt[t][0], z, 0, 0, 0);
        z = __builtin_amdgcn_mfma_f32_16x16x32_bf16(A[m][1], Bt[t][1], z, 0, 0, 0);
        float2v zl = {z[0], z[1]}, zh = {z[2], z[3]};
        float2v ll = __builtin_elementwise_max(zl, zl*0.1f);
        float2v lh = __builtin_elementwise_max(zh, zh*0.1f);
        msg[m][t][0] += hvl*ll;
        msg[m][t][1] += hvh*lh;
      }
    }
  };

  short8 B0[2][2], B1[2][2];
  float bz0[2], bz1[2];
  loadB(0, B0, bz0);
  #pragma unroll 2
  for (int i=0;i<32;i+=2){
    loadB(i+1, B1, bz1);
    compute(i, B0, bz0);
    loadB(i+2, B0, bz0);
    compute(i+1, B1, bz1);
  }

  #pragma unroll
  for (int m=0;m<4;m++)
    #pragma unroll
    for (int r=0;r<4;r++){
      int d = sdst[m*16 + quad*4 + r];
      if (d >= 0){
        #pragma unroll
        for (int t=0;t<2;t++)
          atomAdd(&p.a3[(size_t)d*128 + o0 + t*16 + n], msg[m][t][r>>1][r&1]);
      }
    }
}

// node3 + pool with h2 recomputed per node (a3 = raw conv3 agg); 16 nodes/block.
__global__ __launch_bounds__(256) void npk(P p){
  __shared__ float r3s[8192];
  __shared__ float r2s[512];
  __shared__ float cb2s[64];
  __shared__ float hrow[16][64];
  int tid = threadIdx.x;
  int N = p.N;
  for (int r=tid; r<2048; r+=256)
    reinterpret_cast<float4*>(r3s)[r] = reinterpret_cast<const float4*>(p.root3)[r];
  r2s[tid]     = p.root2[tid];
  r2s[256+tid] = p.root2[256+tid];
  if (tid < 64) cb2s[tid] = p.cb2[tid];
  __syncthreads();

  int n0 = blockIdx.x*16;
  {
    int nl = tid >> 4, c0 = (tid & 15)*4;
    int n = n0 + nl;
    int nn = (n < N) ? n : 0;
    float4 xv  = *reinterpret_cast<const float4*>(p.x  + (size_t)nn*4);
    float4 a1l = *reinterpret_cast<const float4*>(p.a1 + (size_t)nn*8);
    float4 a1h = *reinterpret_cast<const float4*>(p.a1 + (size_t)nn*8 + 4);
    float a1v[8] = {a1l.x,a1l.y,a1l.z,a1l.w,a1h.x,a1h.y,a1h.z,a1h.w};
    float h1[8];
    #pragma unroll
    for (int k=0;k<8;k++){
      float v = a1v[k] + p.cb1[k] + xv.x*p.root1[k] + xv.y*p.root1[8+k]
              + xv.z*p.root1[16+k] + xv.w*p.root1[24+k];
      h1[k] = leaky(v);
    }
    float4 acc = *reinterpret_cast<const float4*>(p.a2 + (size_t)nn*64 + c0);
    float4 cbv = *reinterpret_cast<const float4*>(&cb2s[c0]);
    acc.x+=cbv.x; acc.y+=cbv.y; acc.z+=cbv.z; acc.w+=cbv.w;
    #pragma unroll
    for (int k=0;k<8;k++){
      float hk = h1[k];
      float4 rv = *reinterpret_cast<const float4*>(&r2s[k*64+c0]);
      acc.x += hk*rv.x; acc.y += hk*rv.y; acc.z += hk*rv.z; acc.w += hk*rv.w;
    }
    hrow[nl][c0+0] = leaky(acc.x);
    hrow[nl][c0+1] = leaky(acc.y);
    hrow[nl][c0+2] = leaky(acc.z);
    hrow[nl][c0+3] = leaky(acc.w);
  }
  __syncthreads();

  int o = tid & 127, np_ = tid >> 7;
  float acc = 0.f; int cur = -1;
  for (int rep=0; rep<8; rep++){
    int nl = rep*2 + np_; int n = n0 + nl;
    if (n >= N) break;
    int b = p.batch[n];
    if (b != cur){ if (cur >= 0) atomAdd(&p.g[cur*128+o], acc); acc = 0.f; cur = b; }
    float v = p.a3[(size_t)n*128 + o] + p.cb3[o];
    #pragma unroll 16
    for (int i=0;i<64;i++) v += hrow[nl][i]*r3s[i*128+o];
    acc += leaky(v);
  }
  if (cur >= 0) atomAdd(&p.g[cur*128+o], acc);
}

// readout MLP: one block per graph
__global__ void head_kernel(P p){
  __shared__ float s1[128], s2[128];
  int gi = blockIdx.x, t = threadIdx.x;
  s1[t] = p.g[gi*128+t];
  __syncthreads();
  float v = p.fc1b[t];
  for (int i=0;i<128;i++) v += s1[i]*p.fc1w[i*128+t];
  s2[t] = leaky(v);
  __syncthreads();
  if (t < 64){
    float v2 = p.fc2b[t];
    for (int i=0;i<128;i++) v2 += s2[i]*p.fc2w[i*64+t];
    s1[t] = leaky(v2);
  }
  __syncthreads();
  if (t == 0){
    float v3 = p.fc3b[0];
    for (int i=0;i<64;i++) v3 += s1[i]*p.fc3w[i];
    p.out[gi] = v3;
  }
}

extern "C" void kernel_launch(void* const* d_in, const int* in_sizes, int n_in,
                              void* d_out, int out_size, void* d_ws, size_t ws_size,
                              hipStream_t stream) {
  P p;
  p.x      = (const float*)d_in[0];
  p.ei     = (const int*)  d_in[1];
  p.batch  = (const int*)  d_in[2];
  p.en1_w1 = (const float*)d_in[3];  p.en1_b1 = (const float*)d_in[4];
  p.en1_w2 = (const float*)d_in[5];  p.en1_b2 = (const float*)d_in[6];
  p.en2_w1 = (const float*)d_in[7];  p.en2_b1 = (const float*)d_in[8];
  p.en2_w2 = (const float*)d_in[9];  p.en2_b2 = (const float*)d_in[10];
  p.en3_w1 = (const float*)d_in[11]; p.en3_b1 = (const float*)d_in[12];
  p.en3_w2 = (const float*)d_in[13]; p.en3_b2 = (const float*)d_in[14];
  p.root1  = (const float*)d_in[15]; p.cb1    = (const float*)d_in[16];
  p.root2  = (const float*)d_in[17]; p.cb2    = (const float*)d_in[18];
  p.root3  = (const float*)d_in[19]; p.cb3    = (const float*)d_in[20];
  p.fc1w   = (const float*)d_in[21]; p.fc1b   = (const float*)d_in[22];
  p.fc2w   = (const float*)d_in[23]; p.fc2b   = (const float*)d_in[24];
  p.fc3w   = (const float*)d_in[25]; p.fc3b   = (const float*)d_in[26];
  p.out = (float*)d_out;

  p.N = in_sizes[0] / 4;
  p.E = in_sizes[1] / 2;
  p.Epad = (p.E + 63) & ~63;

  p.ef2b = (short*)d_ws;
  p.ef3b = p.ef2b + (size_t)p.Epad*64;
  p.w2p2 = p.ef3b + (size_t)p.Epad*64;
  p.w2p3 = p.w2p2 + 8*4*2*512;
  p.a1   = (float*)(p.w2p3 + 64*8*2*512);
  p.a2   = p.a1 + (size_t)p.N*8;
  p.a3   = p.a2 + (size_t)p.N*64;
  p.g    = p.a3 + (size_t)p.N*128;

  size_t zero_bytes = ((size_t)p.N*(8+64+128) + (size_t)32*128) * sizeof(float);
  hipMemsetAsync(p.a1, 0, zero_bytes, stream);

  fused0<<<p.Epad/64 + 272, 256, 0, stream>>>(p);
  conv2k<<<p.Epad/32, 256, 0, stream>>>(p);
  conv3k<<<(p.Epad/64)*2, 256, 0, stream>>>(p);
  npk<<<(p.N + 15)/16, 256, 0, stream>>>(p);
  head_kernel<<<32, 128, 0, stream>>>(p);
}